// Round 9
// baseline (131.251 us; speedup 1.0000x reference)
//
#include <hip/hip_runtime.h>

#define GRID_RES 128
#define N_RAYS 65536
#define N_STEPS 128
#define STEP_SIZE 0.001f
#define NVOX (GRID_RES * GRID_RES * GRID_RES)   // 2097152

__device__ __forceinline__ float rcp_fast(float x) {
    return __builtin_amdgcn_rcpf(x);   // v_rcp_f32, ~1 ulp
}
__device__ __forceinline__ float sigmoidf_fast(float x) {
    return rcp_fast(1.0f + __expf(-x));
}

// DPP quad_perm helpers (cross-lane within aligned groups of 4 lanes)
__device__ __forceinline__ float quad_dpp_xor1(float x) {
    return __int_as_float(__builtin_amdgcn_update_dpp(0, __float_as_int(x), 0xB1, 0xF, 0xF, true)); // [1,0,3,2]
}
__device__ __forceinline__ float quad_dpp_xor2(float x) {
    return __int_as_float(__builtin_amdgcn_update_dpp(0, __float_as_int(x), 0x4E, 0xF, 0xF, true)); // [2,3,0,1]
}
__device__ __forceinline__ float quad_bcast3(float x) {
    return __int_as_float(__builtin_amdgcn_update_dpp(0, __float_as_int(x), 0xFF, 0xF, 0xF, true)); // [3,3,3,3]
}
__device__ __forceinline__ float quad_sum(float x) {
    x += quad_dpp_xor1(x);
    x += quad_dpp_xor2(x);
    return x;
}

// ---- prepass: sigma-sign bitmask, 1 bit per voxel (256 KB, L2-resident) ----
__global__ __launch_bounds__(256) void sigma_mask_kernel(
    const float* __restrict__ data, unsigned long long* __restrict__ mask)
{
    int v = blockIdx.x * blockDim.x + threadIdx.x;   // grid sized exactly NVOX
    float s = data[28u * (unsigned)v + 27u];
    unsigned long long b = __ballot(s > 0.0f);
    if ((threadIdx.x & 63) == 0) mask[(unsigned)v >> 6] = b;
}

__global__ __launch_bounds__(256, 4) void vr_kernel(
    const float* __restrict__ data,
    const float* __restrict__ origins,
    const float* __restrict__ dirs,
    const float* __restrict__ viewdirs,
    const unsigned long long* __restrict__ mask,
    float* __restrict__ out)
{
    int gid = blockIdx.x * blockDim.x + threadIdx.x;
    int ray = gid >> 2;        // 4 cooperative lanes per ray
    int l   = gid & 3;

    float ox = origins[3*ray+0], oy = origins[3*ray+1], oz = origins[3*ray+2];
    float dx = dirs[3*ray+0],    dy = dirs[3*ray+1],    dz = dirs[3*ray+2];
    float vx = viewdirs[3*ray+0], vy = viewdirs[3*ray+1], vz = viewdirs[3*ray+2];

    // normalize (numpy rounding: no fma contraction, sqrt+divide)
    {
        float s = __fadd_rn(__fadd_rn(__fmul_rn(dx,dx), __fmul_rn(dy,dy)), __fmul_rn(dz,dz));
        float n = sqrtf(s);
        dx = __fdiv_rn(dx, n); dy = __fdiv_rn(dy, n); dz = __fdiv_rn(dz, n);
    }
    {
        float s = __fadd_rn(__fadd_rn(__fmul_rn(vx,vx), __fmul_rn(vy,vy)), __fmul_rn(vz,vz));
        float n = sqrtf(s);
        vx = __fdiv_rn(vx, n); vy = __fdiv_rn(vy, n); vz = __fdiv_rn(vz, n);
    }

    float invx = __fdiv_rn(1.0f, __fadd_rn(dx, 1e-9f));
    float invy = __fdiv_rn(1.0f, __fadd_rn(dy, 1e-9f));
    float invz = __fdiv_rn(1.0f, __fadd_rn(dz, 1e-9f));

    float t1x = __fmul_rn(-ox, invx), t1y = __fmul_rn(-oy, invy), t1z = __fmul_rn(-oz, invz);
    float t2x = __fadd_rn(t1x, invx), t2y = __fadd_rn(t1y, invy), t2z = __fadd_rn(t1z, invz);
    float tmin = fmaxf(fmaxf(fminf(t1x,t2x), fminf(t1y,t2y)), fminf(t1z,t2z));
    tmin = fmaxf(tmin, 0.0f);
    float tmax = fminf(fminf(fmaxf(t1x,t2x), fmaxf(t1y,t2y)), fmaxf(t1z,t2z));
    tmax = fminf(tmax, 1e9f);
    float dt = __fmul_rn(fmaxf(__fsub_rn(tmax, tmin), 0.0f), (1.0f/(float)N_STEPS));
    float delta_t = __fadd_rn(dt, STEP_SIZE);

    // SH basis
    const float sh0 = 0.28209479177387814f;
    float sh1 = -0.4886025119029199f * vy;
    float sh2 =  0.4886025119029199f * vz;
    float sh3 = -0.4886025119029199f * vx;
    float sh4 =  1.0925484305920792f * vx * vy;
    float sh5 = -1.0925484305920792f * vy * vz;
    float sh6 =  0.31539156525252005f * (2.0f*vz*vz - vx*vx - vy*vy);
    float sh7 = -1.0925484305920792f * vx * vz;
    float sh8 =  0.5462742152960396f * (vx*vx - vy*vy);

    // Per-lane channel-routed weights for components c = 8l..8l+7 (zeros off-channel).
    float wr[8], wg_[8], wb[8];
    #pragma unroll
    for (int m = 0; m < 8; ++m) {
        int c  = 8*l + m;
        int cb = c % 9;
        float s = sh0;
        s = (cb==1) ? sh1 : s;
        s = (cb==2) ? sh2 : s;
        s = (cb==3) ? sh3 : s;
        s = (cb==4) ? sh4 : s;
        s = (cb==5) ? sh5 : s;
        s = (cb==6) ? sh6 : s;
        s = (cb==7) ? sh7 : s;
        s = (cb==8) ? sh8 : s;
        wr[m]  = (c < 9)            ? s : 0.0f;
        wg_[m] = (c >= 9 && c < 18) ? s : 0.0f;
        wb[m]  = (c >= 18 && c < 27)? s : 0.0f;
    }

    unsigned offA = 8u * (unsigned)l;
    unsigned offB = (l < 3) ? (8u * (unsigned)l + 4u) : 24u;

    // voxel linear index for step i — bit-identical to the validated chain
    auto linidx = [&](int i) -> unsigned {
        float t = __fadd_rn(tmin, __fmul_rn((float)i + 0.5f, dt));
        float px = __fadd_rn(ox, __fmul_rn(t, dx));
        float py = __fadd_rn(oy, __fmul_rn(t, dy));
        float pz = __fadd_rn(oz, __fmul_rn(t, dz));
        int ix = (int)(px * (float)GRID_RES);
        int iy = (int)(py * (float)GRID_RES);
        int iz = (int)(pz * (float)GRID_RES);
        ix = min(max(ix, 0), GRID_RES-1);
        iy = min(max(iy, 0), GRID_RES-1);
        iz = min(max(iz, 0), GRID_RES-1);
        return (unsigned)(((ix << 7) | iy) << 7 | iz);
    };

    auto maskbit = [&](unsigned lin) -> bool {
        unsigned long long w = mask[lin >> 6];
        return (w >> (lin & 63u)) & 1ull;
    };

    float light = 1.0f;
    float o_r = 0.0f, o_g = 0.0f, o_b = 0.0f;

    // ---- 3-stage pipeline: maskbit(i+2) || gated coeffs(i+1) || shade(i) ----
    unsigned lin1;
    bool b0, b1;
    float4 A0, B0;
    {
        unsigned lin0 = linidx(0);
        lin1 = linidx(1);
        b0 = maskbit(lin0);
        b1 = maskbit(lin1);
        const float* rec0 = b0 ? (data + 28u * lin0) : data;
        A0 = *(const float4*)(rec0 + offA);
        B0 = *(const float4*)(rec0 + offB);
    }

    for (int i = 0; i < N_STEPS; ++i) {
        // stage 1: mask bit two steps ahead (L2-hot 256KB array)
        unsigned lin2 = linidx(i + 2);
        bool b2 = maskbit(lin2);

        // stage 2: coefficients one step ahead, bit-gated via address select
        const float* rec1 = b1 ? (data + 28u * lin1) : data;
        float4 A1 = *(const float4*)(rec1 + offA);
        float4 B1 = *(const float4*)(rec1 + offB);

        // stage 3: shade step i. sigma: comp 27 = lane3's A.w, broadcast via DPP.
        // b0 == (sigma_raw > 0) exactly, so select == relu of the reference.
        float sigma = b0 ? quad_bcast3(A0.w) : 0.0f;
        float att = __expf(-delta_t * sigma);
        float w = light * (1.0f - att);

        float pr = wr[0]*A0.x + wr[1]*A0.y + wr[2]*A0.z + wr[3]*A0.w
                 + wr[4]*B0.x + wr[5]*B0.y + wr[6]*B0.z + wr[7]*B0.w;
        float pg = wg_[0]*A0.x + wg_[1]*A0.y + wg_[2]*A0.z + wg_[3]*A0.w
                 + wg_[4]*B0.x + wg_[5]*B0.y + wg_[6]*B0.z + wg_[7]*B0.w;
        float pb = wb[0]*A0.x + wb[1]*A0.y + wb[2]*A0.z + wb[3]*A0.w
                 + wb[4]*B0.x + wb[5]*B0.y + wb[6]*B0.z + wb[7]*B0.w;

        float r = quad_sum(pr);
        float g = quad_sum(pg);
        float b = quad_sum(pb);

        o_r = fmaf(w, sigmoidf_fast(r), o_r);
        o_g = fmaf(w, sigmoidf_fast(g), o_g);
        o_b = fmaf(w, sigmoidf_fast(b), o_b);
        light *= att;

        // shift (static names only)
        b0 = b1; b1 = b2;
        lin1 = lin2;
        A0 = A1; B0 = B1;
    }

    if (l == 0) {
        out[3*ray+0] = o_r + light;   // BG = 1.0
        out[3*ray+1] = o_g + light;
        out[3*ray+2] = o_b + light;
    }
}

extern "C" void kernel_launch(void* const* d_in, const int* in_sizes, int n_in,
                              void* d_out, int out_size, void* d_ws, size_t ws_size,
                              hipStream_t stream) {
    const float* data     = (const float*)d_in[0];
    const float* origins  = (const float*)d_in[1];
    const float* dirs     = (const float*)d_in[2];
    const float* viewdirs = (const float*)d_in[3];
    float* out = (float*)d_out;

    // ws: sigma-sign bitmask, NVOX bits = 256 KB. Fully rewritten every launch.
    unsigned long long* mask = (unsigned long long*)d_ws;

    sigma_mask_kernel<<<NVOX / 256, 256, 0, stream>>>(data, mask);
    vr_kernel<<<(N_RAYS * 4) / 256, 256, 0, stream>>>(data, origins, dirs, viewdirs, mask, out);
}